// Round 7
// baseline (2149.796 us; speedup 1.0000x reference)
//
#include <hip/hip_runtime.h>
#include <hip/hip_bf16.h>

// Sizes fixed by the problem
#define BB 128
#define SS 1024
#define FF 512
#define HH 128
#define G3 384   // 3*H

typedef __attribute__((ext_vector_type(8))) short bf16x8;
typedef __attribute__((ext_vector_type(4))) float f32x4;

// ---------------------------------------------------------------------------
// lengths: len[b] = #rows t with sum_f x[b,t,f] != 0
// ---------------------------------------------------------------------------
__global__ void zero_len_kernel(int* len) { len[threadIdx.x] = 0; }

__global__ void lengths_kernel(const float* __restrict__ x, int* __restrict__ len) {
    int wave = threadIdx.x >> 6;
    int lane = threadIdx.x & 63;
    long row = (long)blockIdx.x * 4 + wave;   // 0 .. 131071
    const float4* p = (const float4*)&x[row * FF + lane * 8];
    float4 v0 = p[0], v1 = p[1];
    float s = v0.x + v0.y + v0.z + v0.w + v1.x + v1.y + v1.z + v1.w;
    #pragma unroll
    for (int off = 32; off > 0; off >>= 1) s += __shfl_down(s, off, 64);
    if (lane == 0 && s != 0.0f) atomicAdd(&len[row >> 10], 1);
}

// rank[i] = stable rank under descending-length sort (ties -> lower index first)
__global__ void rank_kernel(const int* __restrict__ len, int* __restrict__ rank) {
    int i = threadIdx.x;
    int li = len[i];
    int r = 0;
    for (int jj = 0; jj < BB; jj++) {
        int lj = len[jj];
        if (lj > li || (lj == li && jj < i)) r++;
    }
    rank[i] = r;
}

// ---------------------------------------------------------------------------
// bf16 split helpers (RTN-even rounding; no NaN/inf in this data)
// ---------------------------------------------------------------------------
__device__ __forceinline__ short bf_hi(float w, float& hf) {
    unsigned u = __builtin_bit_cast(unsigned, w);
    unsigned r = (u + 0x7FFFu + ((u >> 16) & 1u)) & 0xFFFF0000u;
    hf = __builtin_bit_cast(float, r);
    return (short)(r >> 16);
}
__device__ __forceinline__ short bf_rn(float w) {
    unsigned u = __builtin_bit_cast(unsigned, w);
    unsigned r = u + 0x7FFFu + ((u >> 16) & 1u);
    return (short)(r >> 16);
}

// ---------------------------------------------------------------------------
// Split-bf16 MFMA GEMM: C[M,N] = A[M,K] @ W[N,K]^T + bias[N]
// (unchanged from round 6; 3-pass hh+hl+lh split -> fp32-grade accuracy)
// ---------------------------------------------------------------------------
__global__ __launch_bounds__(256) void gemm_mfma(
    const float* __restrict__ A, const float* __restrict__ W,
    const float* __restrict__ bias, float* __restrict__ C,
    int M, int N, int K)
{
    const int tid  = threadIdx.x;
    const int wvid = tid >> 6;
    const int lane = tid & 63;
    const int m0   = blockIdx.x * 64 + wvid * 16;
    const int n0   = blockIdx.y * 128;
    const int KS   = K >> 5;

    __shared__ __align__(16) short sh[2][8][64][8];   // [plane][ntile][lane][e] 16KB

    f32x4 acc[8];
    #pragma unroll
    for (int i = 0; i < 8; i++) acc[i] = (f32x4){0.f, 0.f, 0.f, 0.f};

    const int arow = m0 + (lane & 15);
    const int koff = (lane >> 4) << 3;

    for (int ks = 0; ks < KS; ks++) {
        __syncthreads();   // previous iteration's sh reads complete
        #pragma unroll
        for (int i = 0; i < 2; i++) {
            int p  = tid + i * 256;
            int nt = p >> 6, ln = p & 63;
            const float* src = &W[(size_t)(n0 + nt * 16 + (ln & 15)) * K
                                  + ks * 32 + ((ln >> 4) << 3)];
            float w8[8];
            *(float4*)&w8[0] = *(const float4*)&src[0];
            *(float4*)&w8[4] = *(const float4*)&src[4];
            short hi8[8], lo8[8];
            #pragma unroll
            for (int e = 0; e < 8; e++) {
                float hf; hi8[e] = bf_hi(w8[e], hf);
                lo8[e] = bf_rn(w8[e] - hf);
            }
            *(bf16x8*)&sh[0][nt][ln][0] = *(bf16x8*)hi8;
            *(bf16x8*)&sh[1][nt][ln][0] = *(bf16x8*)lo8;
        }
        const float* ap = &A[(size_t)arow * K + ks * 32 + koff];
        float av[8];
        *(float4*)&av[0] = *(const float4*)&ap[0];
        *(float4*)&av[4] = *(const float4*)&ap[4];
        short ah[8], al[8];
        #pragma unroll
        for (int e = 0; e < 8; e++) {
            float hf; ah[e] = bf_hi(av[e], hf);
            al[e] = bf_rn(av[e] - hf);
        }
        bf16x8 ahi = *(bf16x8*)ah, alo = *(bf16x8*)al;
        __syncthreads();   // sh ready
        #pragma unroll
        for (int nt = 0; nt < 8; nt++) {
            bf16x8 bhi = *(bf16x8*)&sh[0][nt][lane][0];
            bf16x8 blo = *(bf16x8*)&sh[1][nt][lane][0];
            acc[nt] = __builtin_amdgcn_mfma_f32_16x16x32_bf16(ahi, bhi, acc[nt], 0, 0, 0);
            acc[nt] = __builtin_amdgcn_mfma_f32_16x16x32_bf16(ahi, blo, acc[nt], 0, 0, 0);
            acc[nt] = __builtin_amdgcn_mfma_f32_16x16x32_bf16(alo, bhi, acc[nt], 0, 0, 0);
        }
    }
    const int crow = m0 + ((lane >> 4) << 2);
    const int ccol = n0 + (lane & 15);
    #pragma unroll
    for (int nt = 0; nt < 8; nt++) {
        int col = ccol + nt * 16;
        float bv = bias[col];
        #pragma unroll
        for (int r = 0; r < 4; r++)
            C[(size_t)(crow + r) * N + col] = acc[nt][r] + bv;
    }
}

// ---------------------------------------------------------------------------
// GRU recurrence, v7. One block (512 thr = 8 waves) per batch row.
// Thread (j = tid>>2, kq = tid&3): owns Whh[{r,z,n} rows j][kq*32 .. +32)
// = 96 floats that must be VGPR-resident.
// v7 fix (round-6 post-mortem): budget was NEVER the binding constraint —
// the scheduler remats/spills loop-INVARIANT values regardless of budget
// (r1: budget 512, still trimmed to 116). A pre-loop asm pin doesn't help:
// it executes once, then the loop reloads from scratch. Fix: pin INSIDE the
// loop. The "+v" asm redefines all 96 weights every iteration -> they become
// LOOP-CARRIED through registers -> remat illegal, spill costs store+load
// per step, so regalloc keeps them resident (launch_bounds(512,1): budget 512).
// ---------------------------------------------------------------------------
__device__ __forceinline__ float fast_sigmoid(float x) {
    return __builtin_amdgcn_rcpf(1.0f + __expf(-x));
}
__device__ __forceinline__ float fast_tanh(float x) {
    return 1.0f - 2.0f * __builtin_amdgcn_rcpf(1.0f + __expf(2.0f * x));
}

template<int FINAL>
__global__ __launch_bounds__(512, 1) void gru_rec(
    const float* __restrict__ xg,    // [B,S,3H]
    const float* __restrict__ Whh,   // [3H,H]
    const float* __restrict__ bhh,   // [3H]
    float* __restrict__ h_out,       // [B,S,H] (FINAL=0) or [B,H] (FINAL=1)
    const int* __restrict__ len,
    const int* __restrict__ rank)
{
    const int b   = blockIdx.x;
    const int tid = threadIdx.x;
    const int j   = tid >> 2;     // 0..127 output lane
    const int kq  = tid & 3;      // K-quarter (32 elems)

    __shared__ __align__(16) float h_lds[2][HH];

    // 3 gates x 32 weights, pre-rotated by 2*kq float4-slots
    float4 wv[3][8];
    #pragma unroll
    for (int g = 0; g < 3; g++) {
        const float4* wr = (const float4*)&Whh[(size_t)(g * HH + j) * HH + kq * 32];
        #pragma unroll
        for (int q = 0; q < 8; q++) wv[g][q] = wr[(q + 2 * kq) & 7];  // runtime idx into GLOBAL mem only
    }

    float b_r = 0.f, b_z = 0.f, b_n = 0.f;
    if (kq == 0) { b_r = bhh[j]; b_z = bhh[HH + j]; b_n = bhh[2 * HH + j]; }
    const float* xgb = xg + (size_t)b * SS * G3;

    if (tid < 2 * HH) ((float*)h_lds)[tid] = 0.0f;
    float hprev = 0.0f, osum = 0.0f;
    const int L = FINAL ? len[b] : 0;

    float xr = 0.f, xz = 0.f, xn = 0.f;
    if (kq == 0) { xr = xgb[j]; xz = xgb[HH + j]; xn = xgb[2 * HH + j]; }
    __syncthreads();

    for (int t = 0; t < SS; t++) {
        // IN-LOOP pin: makes wv loop-carried via registers (see header comment)
        #pragma unroll
        for (int g = 0; g < 3; g++)
            #pragma unroll
            for (int q = 0; q < 8; q++)
                asm volatile("" : "+v"(wv[g][q].x), "+v"(wv[g][q].y),
                                  "+v"(wv[g][q].z), "+v"(wv[g][q].w));

        if (!FINAL && t > 0 && tid >= 64 && tid < 96) {
            int c = tid - 64;
            float4 hv = ((const float4*)h_lds[t & 1])[c];
            *(float4*)&h_out[((size_t)b * SS + (t - 1)) * HH + c * 4] = hv;
        }
        float nxr = 0.f, nxz = 0.f, nxn = 0.f;
        if (kq == 0 && t + 1 < SS) {
            const float* p = xgb + (size_t)(t + 1) * G3;
            nxr = p[j]; nxz = p[HH + j]; nxn = p[2 * HH + j];
        }
        const float4* h4 = (const float4*)h_lds[t & 1];
        float4 ar = {0,0,0,0}, az = {0,0,0,0}, an = {0,0,0,0};
        #pragma unroll
        for (int q = 0; q < 8; q++) {
            float4 hv = h4[kq * 8 + ((q + 2 * kq) & 7)];   // runtime LDS addr: OK
            float4 w0 = wv[0][q], w1 = wv[1][q], w2 = wv[2][q];  // static reg idx
            ar.x = fmaf(w0.x, hv.x, ar.x); ar.y = fmaf(w0.y, hv.y, ar.y);
            ar.z = fmaf(w0.z, hv.z, ar.z); ar.w = fmaf(w0.w, hv.w, ar.w);
            az.x = fmaf(w1.x, hv.x, az.x); az.y = fmaf(w1.y, hv.y, az.y);
            az.z = fmaf(w1.z, hv.z, az.z); az.w = fmaf(w1.w, hv.w, az.w);
            an.x = fmaf(w2.x, hv.x, an.x); an.y = fmaf(w2.y, hv.y, an.y);
            an.z = fmaf(w2.z, hv.z, an.z); an.w = fmaf(w2.w, hv.w, an.w);
        }
        float a0 = (ar.x + ar.y) + (ar.z + ar.w);
        float a1 = (az.x + az.y) + (az.z + az.w);
        float a2 = (an.x + an.y) + (an.z + an.w);
        a0 += __shfl_xor(a0, 1, 64); a1 += __shfl_xor(a1, 1, 64); a2 += __shfl_xor(a2, 1, 64);
        a0 += __shfl_xor(a0, 2, 64); a1 += __shfl_xor(a1, 2, 64); a2 += __shfl_xor(a2, 2, 64);
        if (kq == 0) {
            float r = fast_sigmoid(xr + a0 + b_r);
            float z = fast_sigmoid(xz + a1 + b_z);
            float n = fast_tanh(xn + r * (a2 + b_n));
            float h = (1.0f - z) * n + z * hprev;
            hprev = h;
            h_lds[(t + 1) & 1][j] = h;
            if (FINAL) { if (t < L) osum += h; }
        }
        xr = nxr; xz = nxz; xn = nxn;
        __syncthreads();
    }
    if (!FINAL && tid >= 64 && tid < 96) {
        int c = tid - 64;
        float4 hv = ((const float4*)h_lds[SS & 1])[c];
        *(float4*)&h_out[((size_t)b * SS + (SS - 1)) * HH + c * 4] = hv;
    }
    if (FINAL && kq == 0) {
        h_out[(size_t)rank[b] * HH + j] = osum * (1.0f / (float)SS);
    }
}

// ---------------------------------------------------------------------------
extern "C" void kernel_launch(void* const* d_in, const int* in_sizes, int n_in,
                              void* d_out, int out_size, void* d_ws, size_t ws_size,
                              hipStream_t stream) {
    const float* x    = (const float*)d_in[0];
    const float* Wp   = (const float*)d_in[1];
    const float* bp   = (const float*)d_in[2];
    const float* Wih0 = (const float*)d_in[3];
    const float* Whh0 = (const float*)d_in[4];
    const float* bih0 = (const float*)d_in[5];
    const float* bhh0 = (const float*)d_in[6];
    const float* Wih1 = (const float*)d_in[7];
    const float* Whh1 = (const float*)d_in[8];
    const float* bih1 = (const float*)d_in[9];
    const float* bhh1 = (const float*)d_in[10];
    float* out = (float*)d_out;

    // workspace: [len 128 int][rank 128 int] ... 4KB ... proj/h1 (64MB), xg (192MB)
    int* len  = (int*)d_ws;
    int* rank = len + 128;
    float* proj = (float*)((char*)d_ws + 4096);                  // [B*S, H]  reused as h1
    float* xgb  = proj + (size_t)BB * SS * HH;                   // [B*S, 3H]

    // 1) lengths + rank
    zero_len_kernel<<<1, 128, 0, stream>>>(len);
    lengths_kernel<<<(BB * SS) / 4, 256, 0, stream>>>(x, len);
    rank_kernel<<<1, 128, 0, stream>>>(len, rank);

    // 2) proj = x @ Wp^T + bp       [131072,512] x [128,512]^T
    gemm_mfma<<<dim3(BB * SS / 64, 1), 256, 0, stream>>>(x, Wp, bp, proj,
                                                         BB * SS, HH, FF);
    // 3) xg0 = proj @ Wih0^T + bih0 [131072,128] x [384,128]^T
    gemm_mfma<<<dim3(BB * SS / 64, 3), 256, 0, stream>>>(proj, Wih0, bih0, xgb,
                                                         BB * SS, G3, HH);
    // 4) layer-1 recurrence -> h1 (into proj region; proj is dead now)
    gru_rec<0><<<BB, 512, 0, stream>>>(xgb, Whh0, bhh0, proj, len, rank);

    // 5) xg1 = h1 @ Wih1^T + bih1 (overwrite xg region)
    gemm_mfma<<<dim3(BB * SS / 64, 3), 256, 0, stream>>>(proj, Wih1, bih1, xgb,
                                                         BB * SS, G3, HH);
    // 6) layer-2 recurrence + masked mean -> out at sorted rank
    gru_rec<1><<<BB, 512, 0, stream>>>(xgb, Whh1, bhh1, out, len, rank);
}

// Round 8
// 2058.410 us; speedup vs baseline: 1.0444x; 1.0444x over previous
//
#include <hip/hip_runtime.h>
#include <hip/hip_bf16.h>

// Sizes fixed by the problem
#define BB 128
#define SS 1024
#define FF 512
#define HH 128
#define G3 384   // 3*H

typedef __attribute__((ext_vector_type(8))) short bf16x8;
typedef __attribute__((ext_vector_type(4))) float f32x4;
typedef _Float16 half2_t __attribute__((ext_vector_type(2)));

// ---------------------------------------------------------------------------
// lengths: len[b] = #rows t with sum_f x[b,t,f] != 0
// ---------------------------------------------------------------------------
__global__ void zero_len_kernel(int* len) { len[threadIdx.x] = 0; }

__global__ void lengths_kernel(const float* __restrict__ x, int* __restrict__ len) {
    int wave = threadIdx.x >> 6;
    int lane = threadIdx.x & 63;
    long row = (long)blockIdx.x * 4 + wave;   // 0 .. 131071
    const float4* p = (const float4*)&x[row * FF + lane * 8];
    float4 v0 = p[0], v1 = p[1];
    float s = v0.x + v0.y + v0.z + v0.w + v1.x + v1.y + v1.z + v1.w;
    #pragma unroll
    for (int off = 32; off > 0; off >>= 1) s += __shfl_down(s, off, 64);
    if (lane == 0 && s != 0.0f) atomicAdd(&len[row >> 10], 1);
}

// rank[i] = stable rank under descending-length sort (ties -> lower index first)
__global__ void rank_kernel(const int* __restrict__ len, int* __restrict__ rank) {
    int i = threadIdx.x;
    int li = len[i];
    int r = 0;
    for (int jj = 0; jj < BB; jj++) {
        int lj = len[jj];
        if (lj > li || (lj == li && jj < i)) r++;
    }
    rank[i] = r;
}

// ---------------------------------------------------------------------------
// bf16 split helpers (RTN-even rounding; no NaN/inf in this data)
// ---------------------------------------------------------------------------
__device__ __forceinline__ short bf_hi(float w, float& hf) {
    unsigned u = __builtin_bit_cast(unsigned, w);
    unsigned r = (u + 0x7FFFu + ((u >> 16) & 1u)) & 0xFFFF0000u;
    hf = __builtin_bit_cast(float, r);
    return (short)(r >> 16);
}
__device__ __forceinline__ short bf_rn(float w) {
    unsigned u = __builtin_bit_cast(unsigned, w);
    unsigned r = u + 0x7FFFu + ((u >> 16) & 1u);
    return (short)(r >> 16);
}

// ---------------------------------------------------------------------------
// Split-bf16 MFMA GEMM: C[M,N] = A[M,K] @ W[N,K]^T + bias[N]
// (unchanged from round 6; 3-pass hh+hl+lh split -> fp32-grade accuracy)
// ---------------------------------------------------------------------------
__global__ __launch_bounds__(256) void gemm_mfma(
    const float* __restrict__ A, const float* __restrict__ W,
    const float* __restrict__ bias, float* __restrict__ C,
    int M, int N, int K)
{
    const int tid  = threadIdx.x;
    const int wvid = tid >> 6;
    const int lane = tid & 63;
    const int m0   = blockIdx.x * 64 + wvid * 16;
    const int n0   = blockIdx.y * 128;
    const int KS   = K >> 5;

    __shared__ __align__(16) short sh[2][8][64][8];   // [plane][ntile][lane][e] 16KB

    f32x4 acc[8];
    #pragma unroll
    for (int i = 0; i < 8; i++) acc[i] = (f32x4){0.f, 0.f, 0.f, 0.f};

    const int arow = m0 + (lane & 15);
    const int koff = (lane >> 4) << 3;

    for (int ks = 0; ks < KS; ks++) {
        __syncthreads();   // previous iteration's sh reads complete
        #pragma unroll
        for (int i = 0; i < 2; i++) {
            int p  = tid + i * 256;
            int nt = p >> 6, ln = p & 63;
            const float* src = &W[(size_t)(n0 + nt * 16 + (ln & 15)) * K
                                  + ks * 32 + ((ln >> 4) << 3)];
            float w8[8];
            *(float4*)&w8[0] = *(const float4*)&src[0];
            *(float4*)&w8[4] = *(const float4*)&src[4];
            short hi8[8], lo8[8];
            #pragma unroll
            for (int e = 0; e < 8; e++) {
                float hf; hi8[e] = bf_hi(w8[e], hf);
                lo8[e] = bf_rn(w8[e] - hf);
            }
            *(bf16x8*)&sh[0][nt][ln][0] = *(bf16x8*)hi8;
            *(bf16x8*)&sh[1][nt][ln][0] = *(bf16x8*)lo8;
        }
        const float* ap = &A[(size_t)arow * K + ks * 32 + koff];
        float av[8];
        *(float4*)&av[0] = *(const float4*)&ap[0];
        *(float4*)&av[4] = *(const float4*)&ap[4];
        short ah[8], al[8];
        #pragma unroll
        for (int e = 0; e < 8; e++) {
            float hf; ah[e] = bf_hi(av[e], hf);
            al[e] = bf_rn(av[e] - hf);
        }
        bf16x8 ahi = *(bf16x8*)ah, alo = *(bf16x8*)al;
        __syncthreads();   // sh ready
        #pragma unroll
        for (int nt = 0; nt < 8; nt++) {
            bf16x8 bhi = *(bf16x8*)&sh[0][nt][lane][0];
            bf16x8 blo = *(bf16x8*)&sh[1][nt][lane][0];
            acc[nt] = __builtin_amdgcn_mfma_f32_16x16x32_bf16(ahi, bhi, acc[nt], 0, 0, 0);
            acc[nt] = __builtin_amdgcn_mfma_f32_16x16x32_bf16(ahi, blo, acc[nt], 0, 0, 0);
            acc[nt] = __builtin_amdgcn_mfma_f32_16x16x32_bf16(alo, bhi, acc[nt], 0, 0, 0);
        }
    }
    const int crow = m0 + ((lane >> 4) << 2);
    const int ccol = n0 + (lane & 15);
    #pragma unroll
    for (int nt = 0; nt < 8; nt++) {
        int col = ccol + nt * 16;
        float bv = bias[col];
        #pragma unroll
        for (int r = 0; r < 4; r++)
            C[(size_t)(crow + r) * N + col] = acc[nt][r] + bv;
    }
}

// ---------------------------------------------------------------------------
// GRU recurrence, v8: f16 weights + v_dot2_f32_f16.
// Rounds 1-7 post-mortem: the allocator caps this kernel shape at ~76-116
// VGPR regardless of launch_bounds / waves_per_eu / asm pins; with fp32
// weights (96 regs) + working set (~45) the demand exceeded the tier, so it
// evicted the weights -> 192 KB/step/block L2 reloads = 1715 cy/step = the
// whole kernel. Fix: SHRINK DEMAND UNDER THE TIER. Weights as 48 packed
// f16x2 VGPRs (f16 rel err 2^-11; weights ~U(+-0.088), h in (-1,1) -> h
// steady-state error ~1e-4 << 3.2e-3 threshold). fdot2 = 2 MAC/instr also
// halves the dot-issue floor. h staged in LDS as f16 (dots) + fp32 (lagged
// coalesced h1 writeout). Gate math stays fp32.
// ---------------------------------------------------------------------------
__device__ __forceinline__ float fast_sigmoid(float x) {
    return __builtin_amdgcn_rcpf(1.0f + __expf(-x));
}
__device__ __forceinline__ float fast_tanh(float x) {
    return 1.0f - 2.0f * __builtin_amdgcn_rcpf(1.0f + __expf(2.0f * x));
}
__device__ __forceinline__ half2_t bc16(unsigned u) {
    return __builtin_bit_cast(half2_t, u);
}
__device__ __forceinline__ unsigned pk16(float x, float y) {
    half2_t h; h[0] = (_Float16)x; h[1] = (_Float16)y;
    return __builtin_bit_cast(unsigned, h);
}
__device__ __forceinline__ float fdot2_(half2_t a, half2_t b, float c) {
#if __has_builtin(__builtin_amdgcn_fdot2)
    return __builtin_amdgcn_fdot2(a, b, c, false);
#else
    return c + (float)a[0] * (float)b[0] + (float)a[1] * (float)b[1];
#endif
}

template<int FINAL>
__global__ __launch_bounds__(512, 1) void gru_rec(
    const float* __restrict__ xg,    // [B,S,3H]
    const float* __restrict__ Whh,   // [3H,H]
    const float* __restrict__ bhh,   // [3H]
    float* __restrict__ h_out,       // [B,S,H] (FINAL=0) or [B,H] (FINAL=1)
    const int* __restrict__ len,
    const int* __restrict__ rank)
{
    const int b   = blockIdx.x;
    const int tid = threadIdx.x;
    const int j   = tid >> 2;     // 0..127 output lane
    const int kq  = tid & 3;      // K-quarter (32 elems = 16 f16 pairs)

    __shared__ __align__(16) _Float16 h16[2][HH];   // f16 hidden for dots
    __shared__ __align__(16) float    h32[2][HH];   // fp32 hidden for writeout

    // 3 gates x 16 f16-pair weights = 48 VGPRs
    unsigned wv[3][16];
    #pragma unroll
    for (int g = 0; g < 3; g++) {
        const float* wr = &Whh[(size_t)(g * HH + j) * HH + kq * 32];
        #pragma unroll
        for (int m = 0; m < 16; m++) wv[g][m] = pk16(wr[2 * m], wr[2 * m + 1]);
    }

    float b_r = 0.f, b_z = 0.f, b_n = 0.f;
    if (kq == 0) { b_r = bhh[j]; b_z = bhh[HH + j]; b_n = bhh[2 * HH + j]; }
    const float* xgb = xg + (size_t)b * SS * G3;

    if (tid < HH) { h16[0][tid] = (_Float16)0.f; h32[0][tid] = 0.f; }
    float hprev = 0.0f, osum = 0.0f;
    const int L = FINAL ? len[b] : 0;

    float xr = 0.f, xz = 0.f, xn = 0.f;
    if (kq == 0) { xr = xgb[j]; xz = xgb[HH + j]; xn = xgb[2 * HH + j]; }
    __syncthreads();

    for (int t = 0; t < SS; t++) {
        // in-loop pin: keep the 48 packed weights loop-carried in VGPRs
        #pragma unroll
        for (int g = 0; g < 3; g++)
            #pragma unroll
            for (int m = 0; m < 16; m += 4)
                asm volatile("" : "+v"(wv[g][m]), "+v"(wv[g][m + 1]),
                                  "+v"(wv[g][m + 2]), "+v"(wv[g][m + 3]));

        // lagged coalesced global write of h_t (wave 1) from fp32 buffer
        if (!FINAL && t > 0 && tid >= 64 && tid < 96) {
            int c = tid - 64;
            float4 hv = ((const float4*)h32[t & 1])[c];
            *(float4*)&h_out[((size_t)b * SS + (t - 1)) * HH + c * 4] = hv;
        }
        // prefetch xg for t+1
        float nxr = 0.f, nxz = 0.f, nxn = 0.f;
        if (kq == 0 && t + 1 < SS) {
            const float* p = xgb + (size_t)(t + 1) * G3;
            nxr = p[j]; nxz = p[HH + j]; nxn = p[2 * HH + j];
        }
        // matvec: 3 gates x 16 fdot2, two chains per gate (i even/odd)
        const unsigned* hp = (const unsigned*)(&h16[t & 1][0]) + kq * 16;
        float a0 = 0.f, a1 = 0.f, a2 = 0.f;   // chain A (i = 0,2)
        float c0 = 0.f, c1 = 0.f, c2 = 0.f;   // chain B (i = 1,3)
        #pragma unroll
        for (int i = 0; i < 4; i++) {
            uint4 hv = *(const uint4*)(hp + i * 4);
            half2_t q0 = bc16(hv.x), q1 = bc16(hv.y),
                    q2 = bc16(hv.z), q3 = bc16(hv.w);
            if ((i & 1) == 0) {
                a0 = fdot2_(bc16(wv[0][i * 4 + 0]), q0, a0);
                a0 = fdot2_(bc16(wv[0][i * 4 + 1]), q1, a0);
                a0 = fdot2_(bc16(wv[0][i * 4 + 2]), q2, a0);
                a0 = fdot2_(bc16(wv[0][i * 4 + 3]), q3, a0);
                a1 = fdot2_(bc16(wv[1][i * 4 + 0]), q0, a1);
                a1 = fdot2_(bc16(wv[1][i * 4 + 1]), q1, a1);
                a1 = fdot2_(bc16(wv[1][i * 4 + 2]), q2, a1);
                a1 = fdot2_(bc16(wv[1][i * 4 + 3]), q3, a1);
                a2 = fdot2_(bc16(wv[2][i * 4 + 0]), q0, a2);
                a2 = fdot2_(bc16(wv[2][i * 4 + 1]), q1, a2);
                a2 = fdot2_(bc16(wv[2][i * 4 + 2]), q2, a2);
                a2 = fdot2_(bc16(wv[2][i * 4 + 3]), q3, a2);
            } else {
                c0 = fdot2_(bc16(wv[0][i * 4 + 0]), q0, c0);
                c0 = fdot2_(bc16(wv[0][i * 4 + 1]), q1, c0);
                c0 = fdot2_(bc16(wv[0][i * 4 + 2]), q2, c0);
                c0 = fdot2_(bc16(wv[0][i * 4 + 3]), q3, c0);
                c1 = fdot2_(bc16(wv[1][i * 4 + 0]), q0, c1);
                c1 = fdot2_(bc16(wv[1][i * 4 + 1]), q1, c1);
                c1 = fdot2_(bc16(wv[1][i * 4 + 2]), q2, c1);
                c1 = fdot2_(bc16(wv[1][i * 4 + 3]), q3, c1);
                c2 = fdot2_(bc16(wv[2][i * 4 + 0]), q0, c2);
                c2 = fdot2_(bc16(wv[2][i * 4 + 1]), q1, c2);
                c2 = fdot2_(bc16(wv[2][i * 4 + 2]), q2, c2);
                c2 = fdot2_(bc16(wv[2][i * 4 + 3]), q3, c2);
            }
        }
        float s0 = a0 + c0, s1 = a1 + c1, s2 = a2 + c2;
        s0 += __shfl_xor(s0, 1, 64); s1 += __shfl_xor(s1, 1, 64); s2 += __shfl_xor(s2, 1, 64);
        s0 += __shfl_xor(s0, 2, 64); s1 += __shfl_xor(s1, 2, 64); s2 += __shfl_xor(s2, 2, 64);
        if (kq == 0) {
            float r = fast_sigmoid(xr + s0 + b_r);
            float z = fast_sigmoid(xz + s1 + b_z);
            float n = fast_tanh(xn + r * (s2 + b_n));
            float h = (1.0f - z) * n + z * hprev;
            hprev = h;
            h16[(t + 1) & 1][j] = (_Float16)h;
            h32[(t + 1) & 1][j] = h;
            if (FINAL) { if (t < L) osum += h; }
        }
        xr = nxr; xz = nxz; xn = nxn;
        __syncthreads();
    }
    if (!FINAL && tid >= 64 && tid < 96) {
        int c = tid - 64;
        float4 hv = ((const float4*)h32[SS & 1])[c];
        *(float4*)&h_out[((size_t)b * SS + (SS - 1)) * HH + c * 4] = hv;
    }
    if (FINAL && kq == 0) {
        h_out[(size_t)rank[b] * HH + j] = osum * (1.0f / (float)SS);
    }
}

// ---------------------------------------------------------------------------
extern "C" void kernel_launch(void* const* d_in, const int* in_sizes, int n_in,
                              void* d_out, int out_size, void* d_ws, size_t ws_size,
                              hipStream_t stream) {
    const float* x    = (const float*)d_in[0];
    const float* Wp   = (const float*)d_in[1];
    const float* bp   = (const float*)d_in[2];
    const float* Wih0 = (const float*)d_in[3];
    const float* Whh0 = (const float*)d_in[4];
    const float* bih0 = (const float*)d_in[5];
    const float* bhh0 = (const float*)d_in[6];
    const float* Wih1 = (const float*)d_in[7];
    const float* Whh1 = (const float*)d_in[8];
    const float* bih1 = (const float*)d_in[9];
    const float* bhh1 = (const float*)d_in[10];
    float* out = (float*)d_out;

    // workspace: [len 128 int][rank 128 int] ... 4KB ... proj/h1 (64MB), xg (192MB)
    int* len  = (int*)d_ws;
    int* rank = len + 128;
    float* proj = (float*)((char*)d_ws + 4096);                  // [B*S, H]  reused as h1
    float* xgb  = proj + (size_t)BB * SS * HH;                   // [B*S, 3H]

    // 1) lengths + rank
    zero_len_kernel<<<1, 128, 0, stream>>>(len);
    lengths_kernel<<<(BB * SS) / 4, 256, 0, stream>>>(x, len);
    rank_kernel<<<1, 128, 0, stream>>>(len, rank);

    // 2) proj = x @ Wp^T + bp       [131072,512] x [128,512]^T
    gemm_mfma<<<dim3(BB * SS / 64, 1), 256, 0, stream>>>(x, Wp, bp, proj,
                                                         BB * SS, HH, FF);
    // 3) xg0 = proj @ Wih0^T + bih0 [131072,128] x [384,128]^T
    gemm_mfma<<<dim3(BB * SS / 64, 3), 256, 0, stream>>>(proj, Wih0, bih0, xgb,
                                                         BB * SS, G3, HH);
    // 4) layer-1 recurrence -> h1 (into proj region; proj is dead now)
    gru_rec<0><<<BB, 512, 0, stream>>>(xgb, Whh0, bhh0, proj, len, rank);

    // 5) xg1 = h1 @ Wih1^T + bih1 (overwrite xg region)
    gemm_mfma<<<dim3(BB * SS / 64, 3), 256, 0, stream>>>(proj, Wih1, bih1, xgb,
                                                         BB * SS, G3, HH);
    // 6) layer-2 recurrence + masked mean -> out at sorted rank
    gru_rec<1><<<BB, 512, 0, stream>>>(xgb, Whh1, bhh1, out, len, rank);
}